// Round 18
// baseline (353.667 us; speedup 1.0000x reference)
//
#include <hip/hip_runtime.h>
#include <hip/hip_bf16.h>

#define NQL 900
#define CDIM 256
#define BDIM 8
#define LVTOT 21760

typedef __bf16 bf16x8 __attribute__((ext_vector_type(8)));
typedef float f32x4 __attribute__((ext_vector_type(4)));
typedef uint u32x4 __attribute__((ext_vector_type(4)));
typedef uint u32x2 __attribute__((ext_vector_type(2)));

__device__ __forceinline__ ushort f2bf(float x) {
  uint u = __builtin_bit_cast(uint, x);
  u += 0x7fff + ((u >> 16) & 1);
  return (ushort)(u >> 16);
}

// ---------------- bf16 MFMA GEMM (BM=128,BN=128): used for FFN1 (N=2048) ----------------
template <bool ABF16, bool RELU, bool OUTBF16>
__global__ __launch_bounds__(256, 4) void mgemm_kernel(const void* __restrict__ Ap,
                                                       const float* __restrict__ W,
                                                       const float* __restrict__ bias,
                                                       void* __restrict__ Cout,
                                                       int M, int N, int K) {
  __shared__ ushort smem[10240];
  ushort* As = smem;
  ushort* Bs = smem + 5120;
  const int tid = threadIdx.x;
  const int m0 = blockIdx.y * 128, n0 = blockIdx.x * 128;
  const int wv = tid >> 6;
  const int wm = (wv >> 1) * 64, wn = (wv & 1) * 64;
  const int lane = tid & 63;
  const int lr = lane & 15, kq = lane >> 4;

  f32x4 acc[4][4] = {};
  float4 pa[2][2], pb[2][2];
  u32x4 pa16[2];

  auto load_tiles = [&](int k0) {
#pragma unroll
    for (int it = 0; it < 2; ++it) {
      int idx = it * 256 + tid;
      int r = idx >> 2, s = (idx & 3) << 3;
      int gm = min(m0 + r, M - 1);
      if constexpr (ABF16) {
        pa16[it] = *(const u32x4*)((const ushort*)Ap + (size_t)gm * K + k0 + s);
      } else {
        const float* ap = (const float*)Ap + (size_t)gm * K + k0 + s;
        pa[it][0] = *(const float4*)ap;
        pa[it][1] = *(const float4*)(ap + 4);
      }
      int gn = min(n0 + r, N - 1);
      const float* wp = W + (size_t)gn * K + k0 + s;
      pb[it][0] = *(const float4*)wp;
      pb[it][1] = *(const float4*)(wp + 4);
    }
  };

  auto store_tiles = [&]() {
#pragma unroll
    for (int it = 0; it < 2; ++it) {
      int idx = it * 256 + tid;
      int r = idx >> 2, s = (idx & 3) << 3;
      u32x4 u;
      if constexpr (ABF16) {
        u = pa16[it];
      } else {
        u.x = f2bf(pa[it][0].x) | ((uint)f2bf(pa[it][0].y) << 16);
        u.y = f2bf(pa[it][0].z) | ((uint)f2bf(pa[it][0].w) << 16);
        u.z = f2bf(pa[it][1].x) | ((uint)f2bf(pa[it][1].y) << 16);
        u.w = f2bf(pa[it][1].z) | ((uint)f2bf(pa[it][1].w) << 16);
      }
      *(u32x4*)&As[r * 40 + s] = u;
      u32x4 w;
      w.x = f2bf(pb[it][0].x) | ((uint)f2bf(pb[it][0].y) << 16);
      w.y = f2bf(pb[it][0].z) | ((uint)f2bf(pb[it][0].w) << 16);
      w.z = f2bf(pb[it][1].x) | ((uint)f2bf(pb[it][1].y) << 16);
      w.w = f2bf(pb[it][1].z) | ((uint)f2bf(pb[it][1].w) << 16);
      *(u32x4*)&Bs[r * 40 + s] = w;
    }
  };

  load_tiles(0);
  for (int k0 = 0; k0 < K; k0 += 32) {
    store_tiles();
    __syncthreads();
    if (k0 + 32 < K) load_tiles(k0 + 32);
    bf16x8 af[4], bq[4];
#pragma unroll
    for (int m = 0; m < 4; ++m)
      af[m] = __builtin_bit_cast(bf16x8, *(const u32x4*)&As[(wm + m * 16 + lr) * 40 + kq * 8]);
#pragma unroll
    for (int n = 0; n < 4; ++n)
      bq[n] = __builtin_bit_cast(bf16x8, *(const u32x4*)&Bs[(wn + n * 16 + lr) * 40 + kq * 8]);
#pragma unroll
    for (int m = 0; m < 4; ++m)
#pragma unroll
      for (int n = 0; n < 4; ++n)
        acc[m][n] = __builtin_amdgcn_mfma_f32_16x16x32_bf16(af[m], bq[n], acc[m][n], 0, 0, 0);
    __syncthreads();
  }

  if constexpr (OUTBF16) {
    ushort* Cs = smem;  // 64 rows x 136
#pragma unroll
    for (int p = 0; p < 2; ++p) {
      __syncthreads();
      if (wm == p * 64) {
#pragma unroll
        for (int n = 0; n < 4; ++n) {
          int col = wn + n * 16 + lr;
          float bv = bias[n0 + col];
#pragma unroll
          for (int m = 0; m < 4; ++m)
#pragma unroll
            for (int j = 0; j < 4; ++j) {
              float v = acc[m][n][j] + bv;
              if (RELU) v = fmaxf(v, 0.f);
              Cs[(m * 16 + kq * 4 + j) * 136 + col] = f2bf(v);
            }
        }
      }
      __syncthreads();
#pragma unroll
      for (int it = 0; it < 4; ++it) {
        int idx = it * 256 + tid;
        int r = idx >> 4, c = (idx & 15) * 8;
        int grow = m0 + p * 64 + r;
        if (grow < M) {
          u32x4 u = *(const u32x4*)&Cs[r * 136 + c];
          *(u32x4*)((ushort*)Cout + (size_t)grow * N + n0 + c) = u;
        }
      }
    }
  } else {
#pragma unroll
    for (int n = 0; n < 4; ++n) {
      int gcol = n0 + wn + n * 16 + lr;
      float bv = bias[gcol];
#pragma unroll
      for (int m = 0; m < 4; ++m) {
        int rbase = m0 + wm + m * 16 + kq * 4;
#pragma unroll
        for (int j = 0; j < 4; ++j) {
          int grow = rbase + j;
          if (grow >= M) continue;
          float v = acc[m][n][j] + bv;
          if (RELU) v = fmaxf(v, 0.f);
          ((float*)Cout)[(size_t)grow * N + gcol] = v;
        }
      }
    }
  }
}

// ---------------- bf16 MFMA GEMM (BM=64,BN=64): high-occupancy small-GEMM path ----------------
template <bool ABF16, bool RELU, bool HASRES, bool DOSM, bool OUTBF16>
__global__ __launch_bounds__(256, 4) void mgemm64_kernel(const void* __restrict__ Ap,
                                                         const float* __restrict__ A2p,
                                                         int addlim,
                                                         const float* __restrict__ W,
                                                         const float* __restrict__ bias,
                                                         const float* __restrict__ Rres,
                                                         void* __restrict__ Cout,
                                                         int M, int N, int K) {
  __shared__ ushort smem[5120];
  ushort* As = smem;
  ushort* Bs = smem + 2560;
  const int tid = threadIdx.x;
  const int m0 = blockIdx.y * 64, n0 = blockIdx.x * 64;
  const int wv = tid >> 6, lane = tid & 63;
  const int wm = (wv >> 1) * 32, wn = (wv & 1) * 32;
  const int lr = lane & 15, kq = lane >> 4;
  const bool doadd = (A2p != nullptr) && (n0 < addlim);

  f32x4 acc[2][2] = {};
  float4 pa[2], pb[2];
  u32x4 pa16;

  auto load_tiles = [&](int k0) {
    int r = tid >> 2, s = (tid & 3) << 3;
    int gm = min(m0 + r, M - 1);
    if constexpr (ABF16) {
      pa16 = *(const u32x4*)((const ushort*)Ap + (size_t)gm * K + k0 + s);
    } else {
      const float* ap = (const float*)Ap + (size_t)gm * K + k0 + s;
      pa[0] = *(const float4*)ap;
      pa[1] = *(const float4*)(ap + 4);
      if (doadd) {
        const float* ap2 = A2p + (size_t)gm * K + k0 + s;
        float4 q0 = *(const float4*)ap2;
        float4 q1 = *(const float4*)(ap2 + 4);
        pa[0].x += q0.x; pa[0].y += q0.y; pa[0].z += q0.z; pa[0].w += q0.w;
        pa[1].x += q1.x; pa[1].y += q1.y; pa[1].z += q1.z; pa[1].w += q1.w;
      }
    }
    int gn = min(n0 + r, N - 1);
    const float* wp = W + (size_t)gn * K + k0 + s;
    pb[0] = *(const float4*)wp;
    pb[1] = *(const float4*)(wp + 4);
  };

  auto store_tiles = [&]() {
    int r = tid >> 2, s = (tid & 3) << 3;
    u32x4 u;
    if constexpr (ABF16) {
      u = pa16;
    } else {
      u.x = f2bf(pa[0].x) | ((uint)f2bf(pa[0].y) << 16);
      u.y = f2bf(pa[0].z) | ((uint)f2bf(pa[0].w) << 16);
      u.z = f2bf(pa[1].x) | ((uint)f2bf(pa[1].y) << 16);
      u.w = f2bf(pa[1].z) | ((uint)f2bf(pa[1].w) << 16);
    }
    *(u32x4*)&As[r * 40 + s] = u;
    u32x4 w;
    w.x = f2bf(pb[0].x) | ((uint)f2bf(pb[0].y) << 16);
    w.y = f2bf(pb[0].z) | ((uint)f2bf(pb[0].w) << 16);
    w.z = f2bf(pb[1].x) | ((uint)f2bf(pb[1].y) << 16);
    w.w = f2bf(pb[1].z) | ((uint)f2bf(pb[1].w) << 16);
    *(u32x4*)&Bs[r * 40 + s] = w;
  };

  load_tiles(0);
  for (int k0 = 0; k0 < K; k0 += 32) {
    store_tiles();
    __syncthreads();
    if (k0 + 32 < K) load_tiles(k0 + 32);
    bf16x8 af[2], bq[2];
#pragma unroll
    for (int m = 0; m < 2; ++m)
      af[m] = __builtin_bit_cast(bf16x8, *(const u32x4*)&As[(wm + m * 16 + lr) * 40 + kq * 8]);
#pragma unroll
    for (int n = 0; n < 2; ++n)
      bq[n] = __builtin_bit_cast(bf16x8, *(const u32x4*)&Bs[(wn + n * 16 + lr) * 40 + kq * 8]);
#pragma unroll
    for (int m = 0; m < 2; ++m)
#pragma unroll
      for (int n = 0; n < 2; ++n)
        acc[m][n] = __builtin_amdgcn_mfma_f32_16x16x32_bf16(af[m], bq[n], acc[m][n], 0, 0, 0);
    __syncthreads();
  }

  if constexpr (OUTBF16) {
    ushort* Cs = smem;  // 64 x 72
    __syncthreads();
#pragma unroll
    for (int n = 0; n < 2; ++n) {
      int col = wn + n * 16 + lr;
      float bv = bias[n0 + col];
#pragma unroll
      for (int m = 0; m < 2; ++m)
#pragma unroll
        for (int j = 0; j < 4; ++j) {
          float v = acc[m][n][j] + bv;
          if (RELU) v = fmaxf(v, 0.f);
          Cs[(wm + m * 16 + kq * 4 + j) * 72 + col] = f2bf(v);
        }
    }
    __syncthreads();
#pragma unroll
    for (int it = 0; it < 2; ++it) {
      int idx = it * 256 + tid;
      int r = idx >> 3, c = (idx & 7) * 8;
      int grow = m0 + r;
      if (grow < M) {
        u32x4 u = *(const u32x4*)&Cs[r * 72 + c];
        *(u32x4*)((ushort*)Cout + (size_t)grow * N + n0 + c) = u;
      }
    }
  } else {
#pragma unroll
    for (int n = 0; n < 2; ++n) {
      int gcol = n0 + wn + n * 16 + lr;
      float bv = bias[gcol];
#pragma unroll
      for (int m = 0; m < 2; ++m) {
        int rbase = m0 + wm + m * 16 + kq * 4;
#pragma unroll
        for (int j = 0; j < 4; ++j) {
          int grow = rbase + j;
          float v = acc[m][n][j] + bv;
          if constexpr (DOSM) {
            float gmax = v;
#pragma unroll
            for (int w = 1; w < 16; w <<= 1) gmax = fmaxf(gmax, __shfl_xor(gmax, w));
            float e = __expf(v - gmax);
            float gs = e;
#pragma unroll
            for (int w = 1; w < 16; w <<= 1) gs += __shfl_xor(gs, w);
            v = e / gs;
          }
          if (grow >= M) continue;
          if (HASRES) v += Rres[(size_t)grow * N + gcol];
          if (RELU) v = fmaxf(v, 0.f);
          ((float*)Cout)[(size_t)grow * N + gcol] = v;
        }
      }
    }
  }
}

// ---------------- W fp32 -> bf16 fragment-order pre-pack for vproj ----------------
__global__ __launch_bounds__(256) void wconv_frag_kernel(const float* __restrict__ W,
                                                         ushort* __restrict__ Wfrag) {
  int f = blockIdx.x * 256 + threadIdx.x;  // 8192 fragments
  int l = f & 63;
  int t = f >> 6;
  int ks = t & 7;
  int ng = t >> 3;
  int row = ng * 16 + (l & 15);
  int kb = ks * 32 + (l >> 4) * 8;
  const float* src = W + (size_t)row * 256 + kb;
  float4 a = *(const float4*)src;
  float4 b = *(const float4*)(src + 4);
  u32x4 u;
  u.x = f2bf(a.x) | ((uint)f2bf(a.y) << 16);
  u.y = f2bf(a.z) | ((uint)f2bf(a.w) << 16);
  u.z = f2bf(b.x) | ((uint)f2bf(b.y) << 16);
  u.w = f2bf(b.z) | ((uint)f2bf(b.w) << 16);
  *(u32x4*)(Wfrag + (size_t)f * 8) = u;
}

// ---------------- value projection: 2-slab pipelined, fragment-ordered W ----------------
// Split prefetch: next slab's first half issues under the k-loop, second half under the
// store phase (after acc dies). Barrier-free k-loop; coalesced W-fragment loads.
#define VP_NSLAB 2
__global__ __launch_bounds__(256, 4) void vproj_kernel(const float* __restrict__ A,
                                                       const ushort* __restrict__ Wfrag,
                                                       const float* __restrict__ bias,
                                                       ushort* __restrict__ Cout) {
  __shared__ ushort As[64 * 264];
  const int tid = threadIdx.x;
  const int wv = tid >> 6, lane = tid & 63;
  const int lr = lane & 15, kq = lane >> 4;
  const int slab0 = blockIdx.x * VP_NSLAB;  // 2720 slabs, grid 1360

  float4 va[8], vb[8];
  auto issueA = [&](int s) {
    const float* base = A + (size_t)(slab0 + s) * 64 * 256;
#pragma unroll
    for (int it = 0; it < 8; ++it)
      va[it] = *(const float4*)(base + (size_t)(it * 256 + tid) * 4);
  };
  auto issueB = [&](int s) {
    const float* base = A + (size_t)(slab0 + s) * 64 * 256;
#pragma unroll
    for (int it = 0; it < 8; ++it)
      vb[it] = *(const float4*)(base + (size_t)((8 + it) * 256 + tid) * 4);
  };

  issueA(0);
  issueB(0);
#pragma unroll
  for (int s = 0; s < VP_NSLAB; ++s) {
    // stage both halves into As
#pragma unroll
    for (int it = 0; it < 8; ++it) {
      int f4 = it * 256 + tid;
      int row = f4 >> 6, col = (f4 & 63) * 4;
      u32x2 w;
      w.x = f2bf(va[it].x) | ((uint)f2bf(va[it].y) << 16);
      w.y = f2bf(va[it].z) | ((uint)f2bf(va[it].w) << 16);
      *(u32x2*)&As[row * 264 + col] = w;
    }
#pragma unroll
    for (int it = 0; it < 8; ++it) {
      int f4 = (8 + it) * 256 + tid;
      int row = f4 >> 6, col = (f4 & 63) * 4;
      u32x2 w;
      w.x = f2bf(vb[it].x) | ((uint)f2bf(vb[it].y) << 16);
      w.y = f2bf(vb[it].z) | ((uint)f2bf(vb[it].w) << 16);
      *(u32x2*)&As[row * 264 + col] = w;
    }
    __syncthreads();
    if (s + 1 < VP_NSLAB) issueA(s + 1);  // in flight under k-loop

    f32x4 acc[4][4] = {};
#pragma unroll
    for (int k0 = 0; k0 < 256; k0 += 32) {
      const int ks = k0 >> 5;
      u32x4 bw[4];
#pragma unroll
      for (int ng = 0; ng < 4; ++ng) {
        int f = ((wv * 4 + ng) * 8 + ks) * 64 + lane;
        bw[ng] = *(const u32x4*)(Wfrag + (size_t)f * 8);
      }
      bf16x8 af[4];
#pragma unroll
      for (int m = 0; m < 4; ++m)
        af[m] = __builtin_bit_cast(bf16x8, *(const u32x4*)&As[(m * 16 + lr) * 264 + k0 + kq * 8]);
#pragma unroll
      for (int m = 0; m < 4; ++m)
#pragma unroll
        for (int ng = 0; ng < 4; ++ng)
          acc[m][ng] = __builtin_amdgcn_mfma_f32_16x16x32_bf16(
              af[m], __builtin_bit_cast(bf16x8, bw[ng]), acc[m][ng], 0, 0, 0);
    }
    __syncthreads();

    // epilogue pack (consumes acc)
    ushort* Cs = As;
#pragma unroll
    for (int ng = 0; ng < 4; ++ng) {
      int col = wv * 64 + ng * 16 + lr;
      float bv = bias[col];
#pragma unroll
      for (int m = 0; m < 4; ++m)
#pragma unroll
        for (int j = 0; j < 4; ++j)
          Cs[(m * 16 + kq * 4 + j) * 264 + col] = f2bf(acc[m][ng][j] + bv);
    }
    if (s + 1 < VP_NSLAB) issueB(s + 1);  // in flight under store phase
    __syncthreads();
    ushort* cb = Cout + (size_t)(slab0 + s) * 64 * 256;
#pragma unroll
    for (int it = 0; it < 8; ++it) {
      int idx = it * 256 + tid;
      int r = idx >> 5, c = (idx & 31) * 8;
      u32x4 u = *(const u32x4*)&Cs[r * 264 + c];
      *(u32x4*)(cb + (size_t)r * 256 + c) = u;
    }
    __syncthreads();  // As reuse next slab
  }
}

// ---------------- V transpose (reads combined qkv buffer, stride 768, V at +512) ------------
__global__ __launch_bounds__(256) void vt_kernel(const ushort* __restrict__ qkv,
                                                 ushort* __restrict__ vt) {
  __shared__ ushort Ls[64 * 40];
  const int qt = blockIdx.x;
  const int bh = blockIdx.y;
  const int b = bh >> 3, h = bh & 7;
  const int tid = threadIdx.x;
  const int q0 = qt * 64;
  {
    int r = tid >> 2, c = (tid & 3) * 8;
    int gq = min(q0 + r, NQL - 1);
    u32x4 u = *(const u32x4*)(qkv + ((size_t)(b * NQL + gq) * 768) + 512 + h * 32 + c);
    *(u32x4*)&Ls[r * 40 + c] = u;
  }
  __syncthreads();
  {
    int d = tid >> 3, qw = (tid & 7) * 8;
    u32x4 u;
    uint w[8];
#pragma unroll
    for (int j = 0; j < 8; ++j) w[j] = Ls[(qw + j) * 40 + d];
    u.x = w[0] | (w[1] << 16);
    u.y = w[2] | (w[3] << 16);
    u.z = w[4] | (w[5] << 16);
    u.w = w[6] | (w[7] << 16);
    *(u32x4*)(vt + ((size_t)(bh * 32 + d) * 960) + q0 + qw) = u;
  }
}

// ---------------- MFMA flash self-attention (qkv stride 768: Q at +0, K at +256) ------------
__global__ __launch_bounds__(256, 4) void fattn_kernel(const ushort* __restrict__ qkv,
                                                       const ushort* __restrict__ vt,
                                                       float* __restrict__ out) {
  __shared__ ushort Ks[64 * 40];
  __shared__ ushort Vs[32 * 72];
  __shared__ ushort Ps[4][16 * 72];
  const int qt = blockIdx.x, bh = blockIdx.y;
  const int b = bh >> 3, h = bh & 7;
  const int tid = threadIdx.x;
  const int wv = tid >> 6, lane = tid & 63;
  const int lq = lane & 15, hi = lane >> 4;
  const int q0 = qt * 64 + wv * 16;
  const float SC = 0.17677669529663689f;

  bf16x8 qfrag;
  {
    int qrow = min(q0 + lq, NQL - 1);
    qfrag = __builtin_bit_cast(bf16x8,
        *(const u32x4*)(qkv + (size_t)(b * NQL + qrow) * 768 + h * 32 + hi * 8));
  }

  f32x4 o0 = {}, o1 = {};
  float mrow = -1e30f, lrow = 0.f;

  for (int kt = 0; kt < 15; ++kt) {
    const int k0 = kt * 64;
    __syncthreads();
    {
      int r = tid >> 2, c = (tid & 3) * 8;
      int gk = min(k0 + r, NQL - 1);
      u32x4 u = *(const u32x4*)(qkv + (size_t)(b * NQL + gk) * 768 + 256 + h * 32 + c);
      *(u32x4*)&Ks[r * 40 + c] = u;
    }
    {
      int r = tid >> 3, c = (tid & 7) * 8;
      u32x4 u = *(const u32x4*)(vt + (size_t)(bh * 32 + r) * 960 + k0 + c);
      *(u32x4*)&Vs[r * 72 + c] = u;
    }
    __syncthreads();

    f32x4 st[4];
#pragma unroll
    for (int mt = 0; mt < 4; ++mt) {
      bf16x8 kf = __builtin_bit_cast(bf16x8, *(const u32x4*)&Ks[(mt * 16 + lq) * 40 + hi * 8]);
      f32x4 z = {};
      st[mt] = __builtin_amdgcn_mfma_f32_16x16x32_bf16(kf, qfrag, z, 0, 0, 0);
    }
    float sv[4][4];
    float lmax = -1e30f;
#pragma unroll
    for (int mt = 0; mt < 4; ++mt)
#pragma unroll
      for (int j = 0; j < 4; ++j) {
        int key = k0 + mt * 16 + hi * 4 + j;
        float v = st[mt][j] * SC;
        v = (key < NQL) ? v : -1e30f;
        sv[mt][j] = v;
        lmax = fmaxf(lmax, v);
      }
    lmax = fmaxf(lmax, __shfl_xor(lmax, 16));
    lmax = fmaxf(lmax, __shfl_xor(lmax, 32));
    float mnew = fmaxf(mrow, lmax);
    float rs = __expf(mrow - mnew);
    float lsum = 0.f;
    uint pw[4][2];
#pragma unroll
    for (int mt = 0; mt < 4; ++mt) {
      float p0 = __expf(sv[mt][0] - mnew);
      float p1 = __expf(sv[mt][1] - mnew);
      float p2 = __expf(sv[mt][2] - mnew);
      float p3 = __expf(sv[mt][3] - mnew);
      lsum += (p0 + p1) + (p2 + p3);
      pw[mt][0] = f2bf(p0) | ((uint)f2bf(p1) << 16);
      pw[mt][1] = f2bf(p2) | ((uint)f2bf(p3) << 16);
    }
    lsum += __shfl_xor(lsum, 16);
    lsum += __shfl_xor(lsum, 32);
    lrow = lrow * rs + lsum;
    mrow = mnew;
#pragma unroll
    for (int j = 0; j < 4; ++j) {
      float rsj = __shfl(rs, hi * 4 + j);
      o0[j] *= rsj;
      o1[j] *= rsj;
    }
#pragma unroll
    for (int mt = 0; mt < 4; ++mt) {
      u32x2 u;
      u.x = pw[mt][0];
      u.y = pw[mt][1];
      *(u32x2*)&Ps[wv][lq * 72 + mt * 16 + hi * 4] = u;
    }
#pragma unroll
    for (int k2 = 0; k2 < 2; ++k2) {
      bf16x8 pa = __builtin_bit_cast(bf16x8, *(const u32x4*)&Ps[wv][lq * 72 + k2 * 32 + hi * 8]);
      bf16x8 vb0 = __builtin_bit_cast(bf16x8, *(const u32x4*)&Vs[(0 * 16 + lq) * 72 + k2 * 32 + hi * 8]);
      bf16x8 vb1 = __builtin_bit_cast(bf16x8, *(const u32x4*)&Vs[(1 * 16 + lq) * 72 + k2 * 32 + hi * 8]);
      o0 = __builtin_amdgcn_mfma_f32_16x16x32_bf16(pa, vb0, o0, 0, 0, 0);
      o1 = __builtin_amdgcn_mfma_f32_16x16x32_bf16(pa, vb1, o1, 0, 0, 0);
    }
  }

#pragma unroll
  for (int j = 0; j < 4; ++j) {
    float lj = __shfl(lrow, hi * 4 + j);
    float inv = 1.f / lj;
    int gq = q0 + hi * 4 + j;
    if (gq < NQL) {
      float* op = out + (size_t)(b * NQL + gq) * 256 + h * 32;
      op[lq] = o0[j] * inv;
      op[16 + lq] = o1[j] * inv;
    }
  }
}

// ---------------- LayerNorm over 256: one wave per row, no LDS ----------------
__global__ __launch_bounds__(256) void ln_kernel(const float* __restrict__ x,
                                                 const float* __restrict__ s,
                                                 const float* __restrict__ bb,
                                                 float* __restrict__ out, int M) {
  const int wv = threadIdx.x >> 6, lane = threadIdx.x & 63;
  const int row = blockIdx.x * 4 + wv;
  if (row >= M) return;
  const float4 v = *(const float4*)(x + (size_t)row * 256 + lane * 4);
  float s1 = (v.x + v.y) + (v.z + v.w);
  float s2 = (v.x * v.x + v.y * v.y) + (v.z * v.z + v.w * v.w);
#pragma unroll
  for (int w = 1; w < 64; w <<= 1) {
    s1 += __shfl_xor(s1, w);
    s2 += __shfl_xor(s2, w);
  }
  float mean = s1 * (1.f / 256.f);
  float var = s2 * (1.f / 256.f) - mean * mean;
  float inv = rsqrtf(var + 1e-5f);
  float4 sc = *(const float4*)(s + lane * 4);
  float4 bv = *(const float4*)(bb + lane * 4);
  float4 o;
  o.x = (v.x - mean) * inv * sc.x + bv.x;
  o.y = (v.y - mean) * inv * sc.y + bv.y;
  o.z = (v.z - mean) * inv * sc.z + bv.z;
  o.w = (v.w - mean) * inv * sc.w + bv.w;
  *(float4*)(out + (size_t)row * 256 + lane * 4) = o;
}

// ---------------- deformable sampling: 256 threads, XCD-chunked ----------
__global__ __launch_bounds__(256) void deform_kernel(const __hip_bfloat16* __restrict__ value,
                                                     const float* __restrict__ offb,
                                                     const float* __restrict__ awb,
                                                     const float* __restrict__ refp,
                                                     float* __restrict__ dfout) {
  const int Hs[4] = {128, 64, 32, 16};
  const int Stl[4] = {0, 16384, 20480, 21504};
  int bid = blockIdx.x;
  int b = bid & 7;
  int q = bid >> 3;
  int row = b * NQL + q;
  int tid = threadIdx.x;
  int h = tid >> 5, d = tid & 31;
  const float* off = offb + (size_t)row * 256;
  const float* aw = awb + (size_t)row * 128;
  const float* ref = refp + (size_t)row * 8;
  const __hip_bfloat16* vb = value + (size_t)b * LVTOT * 256 + h * 32 + d;
  float acc = 0.f;
#pragma unroll
  for (int l = 0; l < 4; ++l) {
    int Wi = Hs[l], Hi = Hs[l];
    float Wl = (float)Wi, Hl = (float)Hi;
    int st = Stl[l];
    float rx = ref[l * 2 + 0], ry = ref[l * 2 + 1];
#pragma unroll
    for (int p = 0; p < 4; ++p) {
      int oi = ((h * 4 + l) * 4 + p) * 2;
      float x = (rx + off[oi] / Wl) * Wl - 0.5f;
      float y = (ry + off[oi + 1] / Hl) * Hl - 0.5f;
      float w = aw[h * 16 + l * 4 + p];
      float x0f = floorf(x), y0f = floorf(y);
      float wx = x - x0f, wy = y - y0f;
      int xi0 = (int)x0f, yi0 = (int)y0f;
      float samp = 0.f;
#pragma unroll
      for (int dy = 0; dy < 2; ++dy) {
#pragma unroll
        for (int dx = 0; dx < 2; ++dx) {
          int xi = xi0 + dx, yi = yi0 + dy;
          float tw = (dx ? wx : 1.f - wx) * (dy ? wy : 1.f - wy);
          bool valid = (xi >= 0) && (xi < Wi) && (yi >= 0) && (yi < Hi);
          int xc = min(max(xi, 0), Wi - 1);
          int yc = min(max(yi, 0), Hi - 1);
          float vv = __bfloat162float(vb[(size_t)(st + yc * Wi + xc) * 256]);
          samp += valid ? tw * vv : 0.f;
        }
      }
      acc = fmaf(w, samp, acc);
    }
  }
  dfout[(size_t)row * 256 + tid] = acc;
}

extern "C" void kernel_launch(void* const* d_in, const int* in_sizes, int n_in,
                              void* d_out, int out_size, void* d_ws, size_t ws_size,
                              hipStream_t stream) {
  const float* tgt = (const float*)d_in[0];
  const float* memory = (const float*)d_in[1];
  const float* qpos = (const float*)d_in[2];
  const float* refp = (const float*)d_in[3];
  const float* sa_in_w = (const float*)d_in[4];
  const float* sa_in_b = (const float*)d_in[5];
  const float* sa_out_w = (const float*)d_in[6];
  const float* sa_out_b = (const float*)d_in[7];
  const float* off_w = (const float*)d_in[8];
  const float* off_b = (const float*)d_in[9];
  const float* aw_w = (const float*)d_in[10];
  const float* aw_b = (const float*)d_in[11];
  const float* val_w = (const float*)d_in[12];
  const float* val_b = (const float*)d_in[13];
  const float* co_w = (const float*)d_in[14];
  const float* co_b = (const float*)d_in[15];
  const float* l1_w = (const float*)d_in[16];
  const float* l1_b = (const float*)d_in[17];
  const float* l2_w = (const float*)d_in[18];
  const float* l2_b = (const float*)d_in[19];
  const float* ln1_s = (const float*)d_in[20];
  const float* ln1_b = (const float*)d_in[21];
  const float* ln2_s = (const float*)d_in[22];
  const float* ln2_b = (const float*)d_in[23];
  const float* ln3_s = (const float*)d_in[24];
  const float* ln3_b = (const float*)d_in[25];

  float* ws = (float*)d_ws;
  const size_t E = (size_t)BDIM * NQL * CDIM;  // 1,843,200
  // phase SA
  ushort* vt = (ushort*)(ws + E);            // bf16 [64*32][960] in [E,2E)
  float* attn_o = ws + 4 * E;                // [4E,5E)
  ushort* tmp_qkv = (ushort*)(ws + 5 * E);   // bf16 [7200][768] in [5E,8E)
  float* sa_out = ws + 2 * E;                // fp32 [2E,3E)
  // phase deform
  float* offb = ws + E;                      // [E,2E)
  float* awb = ws + 2 * E;                   // [2E,2.5E)
  float* dfout = ws + 3 * E;                 // [3E,4E)
  float* co_out = ws + 4 * E;                // [4E,5E)
  // phase FFN
  ushort* hidden = (ushort*)ws;              // bf16 [7200][2048] = [0,4E)
  float* ffn_o = ws + 4 * E;                 // [4E,5E)
  // persistent
  float* tgt1 = ws + 8 * E;
  float* tgt2 = ws + 9 * E;
  ushort* wbf = (ushort*)(ws + 10 * E);      // bf16 val_w fragment-ordered [8192][8]
  ushort* valbf = (ushort*)(ws + 11 * E);    // bf16 [174080][256]

  const int M = BDIM * NQL;        // 7200
  const int MT = (M + 127) / 128;  // 57
  const int M64 = (M + 63) / 64;   // 113
  const int LNG = (M + 3) / 4;     // 1800
  dim3 blk(256);

  // 0) val_w -> bf16 fragment order (once)
  wconv_frag_kernel<<<32, blk, 0, stream>>>(val_w, wbf);
  // 1) fused q,k,v projection -> bf16 [M][768] (cols<512: A=tgt+qpos; cols>=512: A=tgt)
  mgemm64_kernel<false, false, false, false, true><<<dim3(12, M64), blk, 0, stream>>>(
      tgt, qpos, 512, sa_in_w, sa_in_b, nullptr, tmp_qkv, M, 768, 256);
  // 2) V transpose -> vt
  vt_kernel<<<dim3(15, 64), blk, 0, stream>>>(tmp_qkv, vt);
  // 3) MFMA flash attention (occupancy bump: 256,4)
  fattn_kernel<<<dim3(15, 64), blk, 0, stream>>>(tmp_qkv, vt, attn_o);
  // 4) out projection + residual(tgt) -> sa_out (fp32)
  mgemm64_kernel<false, false, true, false, false><<<dim3(4, M64), blk, 0, stream>>>(
      attn_o, nullptr, 0, sa_out_w, sa_out_b, tgt, sa_out, M, 256, 256);
  // 5) LN1 -> tgt1
  ln_kernel<<<LNG, blk, 0, stream>>>(sa_out, ln1_s, ln1_b, tgt1, M);
  // 6) value projection (2-slab pipelined, fragment-ordered W) -> bf16
  vproj_kernel<<<(BDIM * LVTOT) / (64 * VP_NSLAB), blk, 0, stream>>>(memory, wbf, val_b, valbf);
  // 7) offsets projection (A = tgt1 + qpos)
  mgemm64_kernel<false, false, false, false, false><<<dim3(4, M64), blk, 0, stream>>>(
      tgt1, qpos, 1 << 30, off_w, off_b, nullptr, offb, M, 256, 256);
  // 8) attention-weights projection + fused softmax (A = tgt1 + qpos)
  mgemm64_kernel<false, false, false, true, false><<<dim3(2, M64), blk, 0, stream>>>(
      tgt1, qpos, 1 << 30, aw_w, aw_b, nullptr, awb, M, 128, 256);
  // 9) deformable sampling (XCD-chunked swizzle)
  deform_kernel<<<M, blk, 0, stream>>>((const __hip_bfloat16*)valbf, offb, awb, refp, dfout);
  // 10) co projection + residual(tgt1) -> co_out
  mgemm64_kernel<false, false, true, false, false><<<dim3(4, M64), blk, 0, stream>>>(
      dfout, nullptr, 0, co_w, co_b, tgt1, co_out, M, 256, 256);
  // 11) LN2 -> tgt2
  ln_kernel<<<LNG, blk, 0, stream>>>(co_out, ln2_s, ln2_b, tgt2, M);
  // 12) FFN1 + ReLU -> bf16 hidden
  mgemm_kernel<false, true, true><<<dim3(16, MT), blk, 0, stream>>>(
      tgt2, l1_w, l1_b, hidden, M, 2048, 256);
  // 13) FFN2 + residual(tgt2) -> ffn_o
  mgemm64_kernel<true, false, true, false, false><<<dim3(4, M64), blk, 0, stream>>>(
      hidden, nullptr, 0, l2_w, l2_b, tgt2, ffn_o, M, 256, 2048);
  // 14) LN3 -> out
  ln_kernel<<<LNG, blk, 0, stream>>>(ffn_o, ln3_s, ln3_b, (float*)d_out, M);
}

// Round 19
// 327.886 us; speedup vs baseline: 1.0786x; 1.0786x over previous
//
#include <hip/hip_runtime.h>
#include <hip/hip_bf16.h>

#define NQL 900
#define CDIM 256
#define BDIM 8
#define LVTOT 21760

typedef __bf16 bf16x8 __attribute__((ext_vector_type(8)));
typedef float f32x4 __attribute__((ext_vector_type(4)));
typedef uint u32x4 __attribute__((ext_vector_type(4)));
typedef uint u32x2 __attribute__((ext_vector_type(2)));

__device__ __forceinline__ ushort f2bf(float x) {
  uint u = __builtin_bit_cast(uint, x);
  u += 0x7fff + ((u >> 16) & 1);
  return (ushort)(u >> 16);
}

// ---------------- bf16 MFMA GEMM (BM=128,BN=128): used for FFN1 (N=2048) ----------------
template <bool ABF16, bool RELU, bool OUTBF16>
__global__ __launch_bounds__(256, 4) void mgemm_kernel(const void* __restrict__ Ap,
                                                       const float* __restrict__ W,
                                                       const float* __restrict__ bias,
                                                       void* __restrict__ Cout,
                                                       int M, int N, int K) {
  __shared__ ushort smem[10240];
  ushort* As = smem;
  ushort* Bs = smem + 5120;
  const int tid = threadIdx.x;
  const int m0 = blockIdx.y * 128, n0 = blockIdx.x * 128;
  const int wv = tid >> 6;
  const int wm = (wv >> 1) * 64, wn = (wv & 1) * 64;
  const int lane = tid & 63;
  const int lr = lane & 15, kq = lane >> 4;

  f32x4 acc[4][4] = {};
  float4 pa[2][2], pb[2][2];
  u32x4 pa16[2];

  auto load_tiles = [&](int k0) {
#pragma unroll
    for (int it = 0; it < 2; ++it) {
      int idx = it * 256 + tid;
      int r = idx >> 2, s = (idx & 3) << 3;
      int gm = min(m0 + r, M - 1);
      if constexpr (ABF16) {
        pa16[it] = *(const u32x4*)((const ushort*)Ap + (size_t)gm * K + k0 + s);
      } else {
        const float* ap = (const float*)Ap + (size_t)gm * K + k0 + s;
        pa[it][0] = *(const float4*)ap;
        pa[it][1] = *(const float4*)(ap + 4);
      }
      int gn = min(n0 + r, N - 1);
      const float* wp = W + (size_t)gn * K + k0 + s;
      pb[it][0] = *(const float4*)wp;
      pb[it][1] = *(const float4*)(wp + 4);
    }
  };

  auto store_tiles = [&]() {
#pragma unroll
    for (int it = 0; it < 2; ++it) {
      int idx = it * 256 + tid;
      int r = idx >> 2, s = (idx & 3) << 3;
      u32x4 u;
      if constexpr (ABF16) {
        u = pa16[it];
      } else {
        u.x = f2bf(pa[it][0].x) | ((uint)f2bf(pa[it][0].y) << 16);
        u.y = f2bf(pa[it][0].z) | ((uint)f2bf(pa[it][0].w) << 16);
        u.z = f2bf(pa[it][1].x) | ((uint)f2bf(pa[it][1].y) << 16);
        u.w = f2bf(pa[it][1].z) | ((uint)f2bf(pa[it][1].w) << 16);
      }
      *(u32x4*)&As[r * 40 + s] = u;
      u32x4 w;
      w.x = f2bf(pb[it][0].x) | ((uint)f2bf(pb[it][0].y) << 16);
      w.y = f2bf(pb[it][0].z) | ((uint)f2bf(pb[it][0].w) << 16);
      w.z = f2bf(pb[it][1].x) | ((uint)f2bf(pb[it][1].y) << 16);
      w.w = f2bf(pb[it][1].z) | ((uint)f2bf(pb[it][1].w) << 16);
      *(u32x4*)&Bs[r * 40 + s] = w;
    }
  };

  load_tiles(0);
  for (int k0 = 0; k0 < K; k0 += 32) {
    store_tiles();
    __syncthreads();
    if (k0 + 32 < K) load_tiles(k0 + 32);
    bf16x8 af[4], bq[4];
#pragma unroll
    for (int m = 0; m < 4; ++m)
      af[m] = __builtin_bit_cast(bf16x8, *(const u32x4*)&As[(wm + m * 16 + lr) * 40 + kq * 8]);
#pragma unroll
    for (int n = 0; n < 4; ++n)
      bq[n] = __builtin_bit_cast(bf16x8, *(const u32x4*)&Bs[(wn + n * 16 + lr) * 40 + kq * 8]);
#pragma unroll
    for (int m = 0; m < 4; ++m)
#pragma unroll
      for (int n = 0; n < 4; ++n)
        acc[m][n] = __builtin_amdgcn_mfma_f32_16x16x32_bf16(af[m], bq[n], acc[m][n], 0, 0, 0);
    __syncthreads();
  }

  if constexpr (OUTBF16) {
    ushort* Cs = smem;  // 64 rows x 136
#pragma unroll
    for (int p = 0; p < 2; ++p) {
      __syncthreads();
      if (wm == p * 64) {
#pragma unroll
        for (int n = 0; n < 4; ++n) {
          int col = wn + n * 16 + lr;
          float bv = bias[n0 + col];
#pragma unroll
          for (int m = 0; m < 4; ++m)
#pragma unroll
            for (int j = 0; j < 4; ++j) {
              float v = acc[m][n][j] + bv;
              if (RELU) v = fmaxf(v, 0.f);
              Cs[(m * 16 + kq * 4 + j) * 136 + col] = f2bf(v);
            }
        }
      }
      __syncthreads();
#pragma unroll
      for (int it = 0; it < 4; ++it) {
        int idx = it * 256 + tid;
        int r = idx >> 4, c = (idx & 15) * 8;
        int grow = m0 + p * 64 + r;
        if (grow < M) {
          u32x4 u = *(const u32x4*)&Cs[r * 136 + c];
          *(u32x4*)((ushort*)Cout + (size_t)grow * N + n0 + c) = u;
        }
      }
    }
  } else {
#pragma unroll
    for (int n = 0; n < 4; ++n) {
      int gcol = n0 + wn + n * 16 + lr;
      float bv = bias[gcol];
#pragma unroll
      for (int m = 0; m < 4; ++m) {
        int rbase = m0 + wm + m * 16 + kq * 4;
#pragma unroll
        for (int j = 0; j < 4; ++j) {
          int grow = rbase + j;
          if (grow >= M) continue;
          float v = acc[m][n][j] + bv;
          if (RELU) v = fmaxf(v, 0.f);
          ((float*)Cout)[(size_t)grow * N + gcol] = v;
        }
      }
    }
  }
}

// ---------------- bf16 MFMA GEMM (BM=64,BN=64): high-occupancy small-GEMM path ----------------
template <bool ABF16, bool RELU, bool HASRES, bool DOSM, bool OUTBF16>
__global__ __launch_bounds__(256, 4) void mgemm64_kernel(const void* __restrict__ Ap,
                                                         const float* __restrict__ A2p,
                                                         int addlim,
                                                         const float* __restrict__ W,
                                                         const float* __restrict__ bias,
                                                         const float* __restrict__ Rres,
                                                         void* __restrict__ Cout,
                                                         int M, int N, int K) {
  __shared__ ushort smem[5120];
  ushort* As = smem;
  ushort* Bs = smem + 2560;
  const int tid = threadIdx.x;
  const int m0 = blockIdx.y * 64, n0 = blockIdx.x * 64;
  const int wv = tid >> 6, lane = tid & 63;
  const int wm = (wv >> 1) * 32, wn = (wv & 1) * 32;
  const int lr = lane & 15, kq = lane >> 4;
  const bool doadd = (A2p != nullptr) && (n0 < addlim);

  f32x4 acc[2][2] = {};
  float4 pa[2], pb[2];
  u32x4 pa16;

  auto load_tiles = [&](int k0) {
    int r = tid >> 2, s = (tid & 3) << 3;
    int gm = min(m0 + r, M - 1);
    if constexpr (ABF16) {
      pa16 = *(const u32x4*)((const ushort*)Ap + (size_t)gm * K + k0 + s);
    } else {
      const float* ap = (const float*)Ap + (size_t)gm * K + k0 + s;
      pa[0] = *(const float4*)ap;
      pa[1] = *(const float4*)(ap + 4);
      if (doadd) {
        const float* ap2 = A2p + (size_t)gm * K + k0 + s;
        float4 q0 = *(const float4*)ap2;
        float4 q1 = *(const float4*)(ap2 + 4);
        pa[0].x += q0.x; pa[0].y += q0.y; pa[0].z += q0.z; pa[0].w += q0.w;
        pa[1].x += q1.x; pa[1].y += q1.y; pa[1].z += q1.z; pa[1].w += q1.w;
      }
    }
    int gn = min(n0 + r, N - 1);
    const float* wp = W + (size_t)gn * K + k0 + s;
    pb[0] = *(const float4*)wp;
    pb[1] = *(const float4*)(wp + 4);
  };

  auto store_tiles = [&]() {
    int r = tid >> 2, s = (tid & 3) << 3;
    u32x4 u;
    if constexpr (ABF16) {
      u = pa16;
    } else {
      u.x = f2bf(pa[0].x) | ((uint)f2bf(pa[0].y) << 16);
      u.y = f2bf(pa[0].z) | ((uint)f2bf(pa[0].w) << 16);
      u.z = f2bf(pa[1].x) | ((uint)f2bf(pa[1].y) << 16);
      u.w = f2bf(pa[1].z) | ((uint)f2bf(pa[1].w) << 16);
    }
    *(u32x4*)&As[r * 40 + s] = u;
    u32x4 w;
    w.x = f2bf(pb[0].x) | ((uint)f2bf(pb[0].y) << 16);
    w.y = f2bf(pb[0].z) | ((uint)f2bf(pb[0].w) << 16);
    w.z = f2bf(pb[1].x) | ((uint)f2bf(pb[1].y) << 16);
    w.w = f2bf(pb[1].z) | ((uint)f2bf(pb[1].w) << 16);
    *(u32x4*)&Bs[r * 40 + s] = w;
  };

  load_tiles(0);
  for (int k0 = 0; k0 < K; k0 += 32) {
    store_tiles();
    __syncthreads();
    if (k0 + 32 < K) load_tiles(k0 + 32);
    bf16x8 af[2], bq[2];
#pragma unroll
    for (int m = 0; m < 2; ++m)
      af[m] = __builtin_bit_cast(bf16x8, *(const u32x4*)&As[(wm + m * 16 + lr) * 40 + kq * 8]);
#pragma unroll
    for (int n = 0; n < 2; ++n)
      bq[n] = __builtin_bit_cast(bf16x8, *(const u32x4*)&Bs[(wn + n * 16 + lr) * 40 + kq * 8]);
#pragma unroll
    for (int m = 0; m < 2; ++m)
#pragma unroll
      for (int n = 0; n < 2; ++n)
        acc[m][n] = __builtin_amdgcn_mfma_f32_16x16x32_bf16(af[m], bq[n], acc[m][n], 0, 0, 0);
    __syncthreads();
  }

  if constexpr (OUTBF16) {
    ushort* Cs = smem;  // 64 x 72
    __syncthreads();
#pragma unroll
    for (int n = 0; n < 2; ++n) {
      int col = wn + n * 16 + lr;
      float bv = bias[n0 + col];
#pragma unroll
      for (int m = 0; m < 2; ++m)
#pragma unroll
        for (int j = 0; j < 4; ++j) {
          float v = acc[m][n][j] + bv;
          if (RELU) v = fmaxf(v, 0.f);
          Cs[(wm + m * 16 + kq * 4 + j) * 72 + col] = f2bf(v);
        }
    }
    __syncthreads();
#pragma unroll
    for (int it = 0; it < 2; ++it) {
      int idx = it * 256 + tid;
      int r = idx >> 3, c = (idx & 7) * 8;
      int grow = m0 + r;
      if (grow < M) {
        u32x4 u = *(const u32x4*)&Cs[r * 72 + c];
        *(u32x4*)((ushort*)Cout + (size_t)grow * N + n0 + c) = u;
      }
    }
  } else {
#pragma unroll
    for (int n = 0; n < 2; ++n) {
      int gcol = n0 + wn + n * 16 + lr;
      float bv = bias[gcol];
#pragma unroll
      for (int m = 0; m < 2; ++m) {
        int rbase = m0 + wm + m * 16 + kq * 4;
#pragma unroll
        for (int j = 0; j < 4; ++j) {
          int grow = rbase + j;
          float v = acc[m][n][j] + bv;
          if constexpr (DOSM) {
            float gmax = v;
#pragma unroll
            for (int w = 1; w < 16; w <<= 1) gmax = fmaxf(gmax, __shfl_xor(gmax, w));
            float e = __expf(v - gmax);
            float gs = e;
#pragma unroll
            for (int w = 1; w < 16; w <<= 1) gs += __shfl_xor(gs, w);
            v = e / gs;
          }
          if (grow >= M) continue;
          if (HASRES) v += Rres[(size_t)grow * N + gcol];
          if (RELU) v = fmaxf(v, 0.f);
          ((float*)Cout)[(size_t)grow * N + gcol] = v;
        }
      }
    }
  }
}

// ---------------- W fp32 -> bf16 fragment-order pre-pack for vproj ----------------
__global__ __launch_bounds__(256) void wconv_frag_kernel(const float* __restrict__ W,
                                                         ushort* __restrict__ Wfrag) {
  int f = blockIdx.x * 256 + threadIdx.x;  // 8192 fragments
  int l = f & 63;
  int t = f >> 6;
  int ks = t & 7;
  int ng = t >> 3;
  int row = ng * 16 + (l & 15);
  int kb = ks * 32 + (l >> 4) * 8;
  const float* src = W + (size_t)row * 256 + kb;
  float4 a = *(const float4*)src;
  float4 b = *(const float4*)(src + 4);
  u32x4 u;
  u.x = f2bf(a.x) | ((uint)f2bf(a.y) << 16);
  u.y = f2bf(a.z) | ((uint)f2bf(a.w) << 16);
  u.z = f2bf(b.x) | ((uint)f2bf(b.y) << 16);
  u.w = f2bf(b.z) | ((uint)f2bf(b.w) << 16);
  *(u32x4*)(Wfrag + (size_t)f * 8) = u;
}

// ---------------- value projection: barrier-free k-loop, fragment-ordered W (R17 best) ------
__global__ __launch_bounds__(256, 4) void vproj_kernel(const float* __restrict__ A,
                                                       const ushort* __restrict__ Wfrag,
                                                       const float* __restrict__ bias,
                                                       ushort* __restrict__ Cout) {
  __shared__ ushort As[64 * 264];
  const int tid = threadIdx.x;
  const int m0 = blockIdx.x * 64;
  const int wv = tid >> 6, lane = tid & 63;
  const int lr = lane & 15, kq = lane >> 4;

  {
    const float* base = A + (size_t)m0 * 256;
    float4 v[16];
#pragma unroll
    for (int it = 0; it < 16; ++it)
      v[it] = *(const float4*)(base + (size_t)(it * 256 + tid) * 4);
#pragma unroll
    for (int it = 0; it < 16; ++it) {
      int f4 = it * 256 + tid;
      int row = f4 >> 6;
      int col = (f4 & 63) * 4;
      u32x2 w;
      w.x = f2bf(v[it].x) | ((uint)f2bf(v[it].y) << 16);
      w.y = f2bf(v[it].z) | ((uint)f2bf(v[it].w) << 16);
      *(u32x2*)&As[row * 264 + col] = w;
    }
  }
  __syncthreads();

  // wave wv owns col-groups ng' = wv*4 + ng (cols wv*64 .. +64)
  f32x4 acc[4][4] = {};
#pragma unroll
  for (int k0 = 0; k0 < 256; k0 += 32) {
    const int ks = k0 >> 5;
    u32x4 bw[4];
#pragma unroll
    for (int ng = 0; ng < 4; ++ng) {
      int f = ((wv * 4 + ng) * 8 + ks) * 64 + lane;
      bw[ng] = *(const u32x4*)(Wfrag + (size_t)f * 8);
    }
    bf16x8 af[4];
#pragma unroll
    for (int m = 0; m < 4; ++m)
      af[m] = __builtin_bit_cast(bf16x8, *(const u32x4*)&As[(m * 16 + lr) * 264 + k0 + kq * 8]);
#pragma unroll
    for (int m = 0; m < 4; ++m)
#pragma unroll
      for (int ng = 0; ng < 4; ++ng)
        acc[m][ng] = __builtin_amdgcn_mfma_f32_16x16x32_bf16(
            af[m], __builtin_bit_cast(bf16x8, bw[ng]), acc[m][ng], 0, 0, 0);
  }
  __syncthreads();

  ushort* Cs = As;
#pragma unroll
  for (int ng = 0; ng < 4; ++ng) {
    int col = wv * 64 + ng * 16 + lr;
    float bv = bias[col];
#pragma unroll
    for (int m = 0; m < 4; ++m)
#pragma unroll
      for (int j = 0; j < 4; ++j)
        Cs[(m * 16 + kq * 4 + j) * 264 + col] = f2bf(acc[m][ng][j] + bv);
  }
  __syncthreads();
#pragma unroll
  for (int it = 0; it < 8; ++it) {
    int idx = it * 256 + tid;
    int r = idx >> 5, c = (idx & 31) * 8;
    u32x4 u = *(const u32x4*)&Cs[r * 264 + c];
    *(u32x4*)(Cout + (size_t)(m0 + r) * 256 + c) = u;
  }
}

// ---------------- V transpose (reads combined qkv buffer, stride 768, V at +512) ------------
__global__ __launch_bounds__(256) void vt_kernel(const ushort* __restrict__ qkv,
                                                 ushort* __restrict__ vt) {
  __shared__ ushort Ls[64 * 40];
  const int qt = blockIdx.x;
  const int bh = blockIdx.y;
  const int b = bh >> 3, h = bh & 7;
  const int tid = threadIdx.x;
  const int q0 = qt * 64;
  {
    int r = tid >> 2, c = (tid & 3) * 8;
    int gq = min(q0 + r, NQL - 1);
    u32x4 u = *(const u32x4*)(qkv + ((size_t)(b * NQL + gq) * 768) + 512 + h * 32 + c);
    *(u32x4*)&Ls[r * 40 + c] = u;
  }
  __syncthreads();
  {
    int d = tid >> 3, qw = (tid & 7) * 8;
    u32x4 u;
    uint w[8];
#pragma unroll
    for (int j = 0; j < 8; ++j) w[j] = Ls[(qw + j) * 40 + d];
    u.x = w[0] | (w[1] << 16);
    u.y = w[2] | (w[3] << 16);
    u.z = w[4] | (w[5] << 16);
    u.w = w[6] | (w[7] << 16);
    *(u32x4*)(vt + ((size_t)(bh * 32 + d) * 960) + q0 + qw) = u;
  }
}

// ---------------- MFMA flash self-attention (qkv stride 768: Q at +0, K at +256) ------------
__global__ __launch_bounds__(256, 2) void fattn_kernel(const ushort* __restrict__ qkv,
                                                       const ushort* __restrict__ vt,
                                                       float* __restrict__ out) {
  __shared__ ushort Ks[64 * 40];
  __shared__ ushort Vs[32 * 72];
  __shared__ ushort Ps[4][16 * 72];
  const int qt = blockIdx.x, bh = blockIdx.y;
  const int b = bh >> 3, h = bh & 7;
  const int tid = threadIdx.x;
  const int wv = tid >> 6, lane = tid & 63;
  const int lq = lane & 15, hi = lane >> 4;
  const int q0 = qt * 64 + wv * 16;
  const float SC = 0.17677669529663689f;

  bf16x8 qfrag;
  {
    int qrow = min(q0 + lq, NQL - 1);
    qfrag = __builtin_bit_cast(bf16x8,
        *(const u32x4*)(qkv + (size_t)(b * NQL + qrow) * 768 + h * 32 + hi * 8));
  }

  f32x4 o0 = {}, o1 = {};
  float mrow = -1e30f, lrow = 0.f;

  for (int kt = 0; kt < 15; ++kt) {
    const int k0 = kt * 64;
    __syncthreads();
    {
      int r = tid >> 2, c = (tid & 3) * 8;
      int gk = min(k0 + r, NQL - 1);
      u32x4 u = *(const u32x4*)(qkv + (size_t)(b * NQL + gk) * 768 + 256 + h * 32 + c);
      *(u32x4*)&Ks[r * 40 + c] = u;
    }
    {
      int r = tid >> 3, c = (tid & 7) * 8;
      u32x4 u = *(const u32x4*)(vt + (size_t)(bh * 32 + r) * 960 + k0 + c);
      *(u32x4*)&Vs[r * 72 + c] = u;
    }
    __syncthreads();

    f32x4 st[4];
#pragma unroll
    for (int mt = 0; mt < 4; ++mt) {
      bf16x8 kf = __builtin_bit_cast(bf16x8, *(const u32x4*)&Ks[(mt * 16 + lq) * 40 + hi * 8]);
      f32x4 z = {};
      st[mt] = __builtin_amdgcn_mfma_f32_16x16x32_bf16(kf, qfrag, z, 0, 0, 0);
    }
    float sv[4][4];
    float lmax = -1e30f;
#pragma unroll
    for (int mt = 0; mt < 4; ++mt)
#pragma unroll
      for (int j = 0; j < 4; ++j) {
        int key = k0 + mt * 16 + hi * 4 + j;
        float v = st[mt][j] * SC;
        v = (key < NQL) ? v : -1e30f;
        sv[mt][j] = v;
        lmax = fmaxf(lmax, v);
      }
    lmax = fmaxf(lmax, __shfl_xor(lmax, 16));
    lmax = fmaxf(lmax, __shfl_xor(lmax, 32));
    float mnew = fmaxf(mrow, lmax);
    float rs = __expf(mrow - mnew);
    float lsum = 0.f;
    uint pw[4][2];
#pragma unroll
    for (int mt = 0; mt < 4; ++mt) {
      float p0 = __expf(sv[mt][0] - mnew);
      float p1 = __expf(sv[mt][1] - mnew);
      float p2 = __expf(sv[mt][2] - mnew);
      float p3 = __expf(sv[mt][3] - mnew);
      lsum += (p0 + p1) + (p2 + p3);
      pw[mt][0] = f2bf(p0) | ((uint)f2bf(p1) << 16);
      pw[mt][1] = f2bf(p2) | ((uint)f2bf(p3) << 16);
    }
    lsum += __shfl_xor(lsum, 16);
    lsum += __shfl_xor(lsum, 32);
    lrow = lrow * rs + lsum;
    mrow = mnew;
#pragma unroll
    for (int j = 0; j < 4; ++j) {
      float rsj = __shfl(rs, hi * 4 + j);
      o0[j] *= rsj;
      o1[j] *= rsj;
    }
#pragma unroll
    for (int mt = 0; mt < 4; ++mt) {
      u32x2 u;
      u.x = pw[mt][0];
      u.y = pw[mt][1];
      *(u32x2*)&Ps[wv][lq * 72 + mt * 16 + hi * 4] = u;
    }
#pragma unroll
    for (int k2 = 0; k2 < 2; ++k2) {
      bf16x8 pa = __builtin_bit_cast(bf16x8, *(const u32x4*)&Ps[wv][lq * 72 + k2 * 32 + hi * 8]);
      bf16x8 vb0 = __builtin_bit_cast(bf16x8, *(const u32x4*)&Vs[(0 * 16 + lq) * 72 + k2 * 32 + hi * 8]);
      bf16x8 vb1 = __builtin_bit_cast(bf16x8, *(const u32x4*)&Vs[(1 * 16 + lq) * 72 + k2 * 32 + hi * 8]);
      o0 = __builtin_amdgcn_mfma_f32_16x16x32_bf16(pa, vb0, o0, 0, 0, 0);
      o1 = __builtin_amdgcn_mfma_f32_16x16x32_bf16(pa, vb1, o1, 0, 0, 0);
    }
  }

#pragma unroll
  for (int j = 0; j < 4; ++j) {
    float lj = __shfl(lrow, hi * 4 + j);
    float inv = 1.f / lj;
    int gq = q0 + hi * 4 + j;
    if (gq < NQL) {
      float* op = out + (size_t)(b * NQL + gq) * 256 + h * 32;
      op[lq] = o0[j] * inv;
      op[16 + lq] = o1[j] * inv;
    }
  }
}

// ---------------- LayerNorm over 256: one wave per row, no LDS ----------------
__global__ __launch_bounds__(256) void ln_kernel(const float* __restrict__ x,
                                                 const float* __restrict__ s,
                                                 const float* __restrict__ bb,
                                                 float* __restrict__ out, int M) {
  const int wv = threadIdx.x >> 6, lane = threadIdx.x & 63;
  const int row = blockIdx.x * 4 + wv;
  if (row >= M) return;
  const float4 v = *(const float4*)(x + (size_t)row * 256 + lane * 4);
  float s1 = (v.x + v.y) + (v.z + v.w);
  float s2 = (v.x * v.x + v.y * v.y) + (v.z * v.z + v.w * v.w);
#pragma unroll
  for (int w = 1; w < 64; w <<= 1) {
    s1 += __shfl_xor(s1, w);
    s2 += __shfl_xor(s2, w);
  }
  float mean = s1 * (1.f / 256.f);
  float var = s2 * (1.f / 256.f) - mean * mean;
  float inv = rsqrtf(var + 1e-5f);
  float4 sc = *(const float4*)(s + lane * 4);
  float4 bv = *(const float4*)(bb + lane * 4);
  float4 o;
  o.x = (v.x - mean) * inv * sc.x + bv.x;
  o.y = (v.y - mean) * inv * sc.y + bv.y;
  o.z = (v.z - mean) * inv * sc.z + bv.z;
  o.w = (v.w - mean) * inv * sc.w + bv.w;
  *(float4*)(out + (size_t)row * 256 + lane * 4) = o;
}

// ---------------- deformable sampling: 256 threads, XCD-chunked ----------
__global__ __launch_bounds__(256) void deform_kernel(const __hip_bfloat16* __restrict__ value,
                                                     const float* __restrict__ offb,
                                                     const float* __restrict__ awb,
                                                     const float* __restrict__ refp,
                                                     float* __restrict__ dfout) {
  const int Hs[4] = {128, 64, 32, 16};
  const int Stl[4] = {0, 16384, 20480, 21504};
  int bid = blockIdx.x;
  int b = bid & 7;
  int q = bid >> 3;
  int row = b * NQL + q;
  int tid = threadIdx.x;
  int h = tid >> 5, d = tid & 31;
  const float* off = offb + (size_t)row * 256;
  const float* aw = awb + (size_t)row * 128;
  const float* ref = refp + (size_t)row * 8;
  const __hip_bfloat16* vb = value + (size_t)b * LVTOT * 256 + h * 32 + d;
  float acc = 0.f;
#pragma unroll
  for (int l = 0; l < 4; ++l) {
    int Wi = Hs[l], Hi = Hs[l];
    float Wl = (float)Wi, Hl = (float)Hi;
    int st = Stl[l];
    float rx = ref[l * 2 + 0], ry = ref[l * 2 + 1];
#pragma unroll
    for (int p = 0; p < 4; ++p) {
      int oi = ((h * 4 + l) * 4 + p) * 2;
      float x = (rx + off[oi] / Wl) * Wl - 0.5f;
      float y = (ry + off[oi + 1] / Hl) * Hl - 0.5f;
      float w = aw[h * 16 + l * 4 + p];
      float x0f = floorf(x), y0f = floorf(y);
      float wx = x - x0f, wy = y - y0f;
      int xi0 = (int)x0f, yi0 = (int)y0f;
      float samp = 0.f;
#pragma unroll
      for (int dy = 0; dy < 2; ++dy) {
#pragma unroll
        for (int dx = 0; dx < 2; ++dx) {
          int xi = xi0 + dx, yi = yi0 + dy;
          float tw = (dx ? wx : 1.f - wx) * (dy ? wy : 1.f - wy);
          bool valid = (xi >= 0) && (xi < Wi) && (yi >= 0) && (yi < Hi);
          int xc = min(max(xi, 0), Wi - 1);
          int yc = min(max(yi, 0), Hi - 1);
          float vv = __bfloat162float(vb[(size_t)(st + yc * Wi + xc) * 256]);
          samp += valid ? tw * vv : 0.f;
        }
      }
      acc = fmaf(w, samp, acc);
    }
  }
  dfout[(size_t)row * 256 + tid] = acc;
}

extern "C" void kernel_launch(void* const* d_in, const int* in_sizes, int n_in,
                              void* d_out, int out_size, void* d_ws, size_t ws_size,
                              hipStream_t stream) {
  const float* tgt = (const float*)d_in[0];
  const float* memory = (const float*)d_in[1];
  const float* qpos = (const float*)d_in[2];
  const float* refp = (const float*)d_in[3];
  const float* sa_in_w = (const float*)d_in[4];
  const float* sa_in_b = (const float*)d_in[5];
  const float* sa_out_w = (const float*)d_in[6];
  const float* sa_out_b = (const float*)d_in[7];
  const float* off_w = (const float*)d_in[8];
  const float* off_b = (const float*)d_in[9];
  const float* aw_w = (const float*)d_in[10];
  const float* aw_b = (const float*)d_in[11];
  const float* val_w = (const float*)d_in[12];
  const float* val_b = (const float*)d_in[13];
  const float* co_w = (const float*)d_in[14];
  const float* co_b = (const float*)d_in[15];
  const float* l1_w = (const float*)d_in[16];
  const float* l1_b = (const float*)d_in[17];
  const float* l2_w = (const float*)d_in[18];
  const float* l2_b = (const float*)d_in[19];
  const float* ln1_s = (const float*)d_in[20];
  const float* ln1_b = (const float*)d_in[21];
  const float* ln2_s = (const float*)d_in[22];
  const float* ln2_b = (const float*)d_in[23];
  const float* ln3_s = (const float*)d_in[24];
  const float* ln3_b = (const float*)d_in[25];

  float* ws = (float*)d_ws;
  const size_t E = (size_t)BDIM * NQL * CDIM;  // 1,843,200
  // phase SA
  ushort* vt = (ushort*)(ws + E);            // bf16 [64*32][960] in [E,2E)
  float* attn_o = ws + 4 * E;                // [4E,5E)
  ushort* tmp_qkv = (ushort*)(ws + 5 * E);   // bf16 [7200][768] in [5E,8E)
  float* sa_out = ws + 2 * E;                // fp32 [2E,3E)
  // phase deform
  float* offb = ws + E;                      // [E,2E)
  float* awb = ws + 2 * E;                   // [2E,2.5E)
  float* dfout = ws + 3 * E;                 // [3E,4E)
  float* co_out = ws + 4 * E;                // [4E,5E)
  // phase FFN
  ushort* hidden = (ushort*)ws;              // bf16 [7200][2048] = [0,4E)
  float* ffn_o = ws + 4 * E;                 // [4E,5E)
  // persistent
  float* tgt1 = ws + 8 * E;
  float* tgt2 = ws + 9 * E;
  ushort* wbf = (ushort*)(ws + 10 * E);      // bf16 val_w fragment-ordered [8192][8]
  ushort* valbf = (ushort*)(ws + 11 * E);    // bf16 [174080][256]

  const int M = BDIM * NQL;        // 7200
  const int MT = (M + 127) / 128;  // 57
  const int M64 = (M + 63) / 64;   // 113
  const int LNG = (M + 3) / 4;     // 1800
  dim3 blk(256);

  // 0) val_w -> bf16 fragment order (once)
  wconv_frag_kernel<<<32, blk, 0, stream>>>(val_w, wbf);
  // 1) fused q,k,v projection -> bf16 [M][768] (cols<512: A=tgt+qpos; cols>=512: A=tgt)
  mgemm64_kernel<false, false, false, false, true><<<dim3(12, M64), blk, 0, stream>>>(
      tgt, qpos, 512, sa_in_w, sa_in_b, nullptr, tmp_qkv, M, 768, 256);
  // 2) V transpose -> vt
  vt_kernel<<<dim3(15, 64), blk, 0, stream>>>(tmp_qkv, vt);
  // 3) MFMA flash attention
  fattn_kernel<<<dim3(15, 64), blk, 0, stream>>>(tmp_qkv, vt, attn_o);
  // 4) out projection + residual(tgt) -> sa_out (fp32)
  mgemm64_kernel<false, false, true, false, false><<<dim3(4, M64), blk, 0, stream>>>(
      attn_o, nullptr, 0, sa_out_w, sa_out_b, tgt, sa_out, M, 256, 256);
  // 5) LN1 -> tgt1
  ln_kernel<<<LNG, blk, 0, stream>>>(sa_out, ln1_s, ln1_b, tgt1, M);
  // 6) value projection (fragment-ordered W) -> bf16
  vproj_kernel<<<(BDIM * LVTOT) / 64, blk, 0, stream>>>(memory, wbf, val_b, valbf);
  // 7) offsets projection (A = tgt1 + qpos)
  mgemm64_kernel<false, false, false, false, false><<<dim3(4, M64), blk, 0, stream>>>(
      tgt1, qpos, 1 << 30, off_w, off_b, nullptr, offb, M, 256, 256);
  // 8) attention-weights projection + fused softmax (A = tgt1 + qpos)
  mgemm64_kernel<false, false, false, true, false><<<dim3(2, M64), blk, 0, stream>>>(
      tgt1, qpos, 1 << 30, aw_w, aw_b, nullptr, awb, M, 128, 256);
  // 9) deformable sampling (XCD-chunked swizzle)
  deform_kernel<<<M, blk, 0, stream>>>((const __hip_bfloat16*)valbf, offb, awb, refp, dfout);
  // 10) co projection + residual(tgt1) -> co_out
  mgemm64_kernel<false, false, true, false, false><<<dim3(4, M64), blk, 0, stream>>>(
      dfout, nullptr, 0, co_w, co_b, tgt1, co_out, M, 256, 256);
  // 11) LN2 -> tgt2
  ln_kernel<<<LNG, blk, 0, stream>>>(co_out, ln2_s, ln2_b, tgt2, M);
  // 12) FFN1 + ReLU -> bf16 hidden
  mgemm_kernel<false, true, true><<<dim3(16, MT), blk, 0, stream>>>(
      tgt2, l1_w, l1_b, hidden, M, 2048, 256);
  // 13) FFN2 + residual(tgt2) -> ffn_o
  mgemm64_kernel<true, false, true, false, false><<<dim3(4, M64), blk, 0, stream>>>(
      hidden, nullptr, 0, l2_w, l2_b, tgt2, ffn_o, M, 256, 2048);
  // 14) LN3 -> out
  ln_kernel<<<LNG, blk, 0, stream>>>(ffn_o, ln3_s, ln3_b, (float*)d_out, M);
}